// Round 5
// baseline (89.244 us; speedup 1.0000x reference)
//
#include <hip/hip_runtime.h>

#define B_TOT 16384
#define F_DIM 512
#define T_DIM 256
#define N_DIM 256
#define NBLK  2048

__device__ __forceinline__ float wave_sum(float v) {
#pragma unroll
    for (int o = 32; o; o >>= 1) v += __shfl_xor(v, o, 64);
    return v;
}
__device__ __forceinline__ float wave_prod(float v) {
#pragma unroll
    for (int o = 32; o; o >>= 1) v *= __shfl_xor(v, o, 64);
    return v;
}
// logp of the chosen logit: chosen - lse(chosen,other) == -log(1+exp(other-chosen))
__device__ __forceinline__ float pick_lp(float chosen, float other) {
    return -__logf(1.f + __expf(other - chosen));
}

// Fused single kernel. Main loop identical in structure to round 3 (24.4us
// version). Tail: plain partial stores -> __threadfence -> relaxed ticket;
// non-last blocks take a BLOCK-UNIFORM early return so every __syncthreads
// sits at top level (round 4's barrier-inside-divergent-if collapsed the
// scheduler to 32 VGPRs and serialized the row loads).
__global__ __launch_bounds__(256, 4) void setcrit_fused(
    const float* __restrict__ pred_class,
    const float* __restrict__ pred_v,
    const float* __restrict__ targets,
    float* __restrict__ partial,
    unsigned int* __restrict__ ctr,
    float* __restrict__ out)
{
    __shared__ float s_predv[4][N_DIM];
    __shared__ float s_fin[4][4];
    __shared__ float s_red[4];
    __shared__ unsigned int s_ticket;

    const int tid = threadIdx.x;
    const int l   = tid & 63;
    const int w   = tid >> 6;
    const unsigned long long lt = (1ull << l) - 1ull;
    const int wave_id = blockIdx.x * 4 + w;   // 8192 waves, 2 rows each

    float acc_pick = 0.f, acc_dsq = 0.f, acc_multi = 0.f;
    int   acc_tc = 0;

#pragma unroll
    for (int i = 0; i < 2; ++i) {
        const int b = i * (NBLK * 4) + wave_id;
        const float* lgp = pred_class + (size_t)b * (2 * F_DIM);
        const float* pvp = pred_v     + (size_t)b * N_DIM;
        const float* tgp = targets    + (size_t)b * T_DIM;

        // ---- issue all row loads up front (independent, coalesced) ----
        float4 g0 = *(const float4*)(lgp + 8 * l);          // f = 4l, 4l+1
        float4 g1 = *(const float4*)(lgp + 8 * l + 4);      // f = 4l+2, 4l+3
        float4 g2 = *(const float4*)(lgp + 512 + 8 * l);    // f = 256+4l, 257+4l
        float4 g3 = *(const float4*)(lgp + 512 + 8 * l + 4);// f = 258+4l, 259+4l
        float4 pv = *(const float4*)(pvp + 4 * l);          // n = 4l..4l+3
        float4 tg = *(const float4*)(tgp + 4 * l);          // t = 4l..4l+3

        *(float4*)(&s_predv[w][4 * l]) = pv;                // stage for gather

        // ---- log-softmax picks: f<256 -> logp[1], f>=256 -> logp[0] ----
        float p = 0.f;
        p += pick_lp(g0.y, g0.x);
        p += pick_lp(g0.w, g0.z);
        p += pick_lp(g1.y, g1.x);
        p += pick_lp(g1.w, g1.z);
        p += pick_lp(g2.x, g2.y);
        p += pick_lp(g2.z, g2.w);
        p += pick_lp(g3.x, g3.y);
        p += pick_lp(g3.w, g3.z);
        acc_pick += p;

        // ---- mask + exclusive prefix over t=4l..4l+3 via 4 ballots ----
        bool m0 = g0.y > g0.x;
        bool m1 = g0.w > g0.z;
        bool m2 = g1.y > g1.x;
        bool m3 = g1.w > g1.z;
        unsigned long long b0 = __ballot(m0);
        unsigned long long b1 = __ballot(m1);
        unsigned long long b2 = __ballot(m2);
        unsigned long long b3 = __ballot(m3);

        int e0 = __popcll(b0 & lt) + __popcll(b1 & lt)
               + __popcll(b2 & lt) + __popcll(b3 & lt);
        int e1 = e0 + (m0 ? 1 : 0);
        int e2 = e1 + (m1 ? 1 : 0);
        int e3 = e2 + (m2 ? 1 : 0);
        acc_tc += __popcll(b0) + __popcll(b1) + __popcll(b2) + __popcll(b3);

        // ---- matched gather + squared error (tc==0 rows contribute 0) ----
        float dsq = 0.f, d;
        if (m0) { d = s_predv[w][e0] - tg.x; dsq += d * d; }
        if (m1) { d = s_predv[w][e1] - tg.y; dsq += d * d; }
        if (m2) { d = s_predv[w][e2] - tg.z; dsq += d * d; }
        if (m3) { d = s_predv[w][e3] - tg.w; dsq += d * d; }
        acc_dsq += dsq;

        // ---- product over the row ----
        float prod = wave_prod(pv.x * pv.y * pv.z * pv.w);
        float pm1 = prod - 1.f;
        acc_multi += pm1 * pm1;
    }

    float pickS = wave_sum(acc_pick);
    float dsqS  = wave_sum(acc_dsq);
    if (l == 0) {
        s_fin[w][0] = pickS;
        s_fin[w][1] = acc_multi;
        s_fin[w][2] = dsqS;
        s_fin[w][3] = (float)acc_tc;
    }
    __syncthreads();

    if (tid == 0) {
        float v0 = 0.f, v1 = 0.f, v2 = 0.f, v3 = 0.f;
#pragma unroll
        for (int k = 0; k < 4; ++k) {
            v0 += s_fin[k][0]; v1 += s_fin[k][1];
            v2 += s_fin[k][2]; v3 += s_fin[k][3];
        }
        partial[0 * NBLK + blockIdx.x] = v0;
        partial[1 * NBLK + blockIdx.x] = v1;
        partial[2 * NBLK + blockIdx.x] = v2 * (1.f / (float)T_DIM);
        partial[3 * NBLK + blockIdx.x] = v3 * (1.f / (float)T_DIM);
        __threadfence();                         // publish partials (agent scope)
        s_ticket = atomicAdd(ctr, 1u);           // device-scope by default
    }
    __syncthreads();

    if (s_ticket != NBLK - 1) return;            // block-uniform exit

    // ---- last block: deterministic final reduction, barriers at top level ----
    __threadfence();
    float v = 0.f;
#pragma unroll
    for (int i = 0; i < NBLK / 64; ++i)
        v += __hip_atomic_load(&partial[w * NBLK + i * 64 + l],
                               __ATOMIC_RELAXED, __HIP_MEMORY_SCOPE_AGENT);
    v = wave_sum(v);
    if (l == 0) s_red[w] = v;
    __syncthreads();

    if (tid == 0) {
        float loss_label = -s_red[0] / ((float)B_TOT * (float)F_DIM);
        float loss_multi = s_red[1] / (float)B_TOT;
        float loss_true  = s_red[2] / (float)B_TOT;
        float f1         = s_red[3] / (float)B_TOT;
        float r = loss_multi + loss_true;
        out[0] = loss_label + r;
        out[1] = loss_label;
        out[2] = r;
        out[3] = loss_multi;
        out[4] = loss_true;
        out[5] = f1;
    }
}

extern "C" void kernel_launch(void* const* d_in, const int* in_sizes, int n_in,
                              void* d_out, int out_size, void* d_ws, size_t ws_size,
                              hipStream_t stream) {
    const float* pred_class = (const float*)d_in[0];
    const float* pred_v     = (const float*)d_in[1];
    const float* targets    = (const float*)d_in[2];

    float* partial = (float*)d_ws;                        // 4*NBLK floats = 32 KB
    unsigned int* ctr = (unsigned int*)((char*)d_ws + 4 * NBLK * sizeof(float));

    hipMemsetAsync(ctr, 0, sizeof(unsigned int), stream); // reset ticket each call
    setcrit_fused<<<NBLK, 256, 0, stream>>>(pred_class, pred_v, targets,
                                            partial, ctr, (float*)d_out);
}

// Round 6
// 43.495 us; speedup vs baseline: 2.0518x; 2.0518x over previous
//
#include <hip/hip_runtime.h>

#define B_TOT 16384
#define F_DIM 512
#define T_DIM 256
#define N_DIM 256
#define NBLK  2048

__device__ __forceinline__ float wave_sum(float v) {
#pragma unroll
    for (int o = 32; o; o >>= 1) v += __shfl_xor(v, o, 64);
    return v;
}
__device__ __forceinline__ float wave_prod(float v) {
#pragma unroll
    for (int o = 32; o; o >>= 1) v *= __shfl_xor(v, o, 64);
    return v;
}
// logp of the chosen logit: chosen - lse(chosen,other) == -log(1+exp(other-chosen))
__device__ __forceinline__ float pick_lp(float chosen, float other) {
    return -__logf(1.f + __expf(other - chosen));
}

// Fused single kernel, NO cache-maintenance ops anywhere:
//  - rounds 4/5 ran 3.6x slower because each block's release fence
//    (__threadfence / ACQ_REL RMW) emits buffer_wbl2[+inv] = full L2
//    writeback/invalidate x2048, poisoning the stream (L3-warm replays were
//    equally slow -> latency poison, not bandwidth).
//  - here: partials published via RELAXED agent-scope atomic stores (sc1
//    write-through, no L2 flush); manual release = s_waitcnt vmcnt(0) before a
//    RELAXED agent-scope ticket RMW; reader uses relaxed agent-scope atomic
//    loads (bypass stale local L2). Deterministic fixed-order final sum.
__global__ __launch_bounds__(256, 4) void setcrit_fused(
    const float* __restrict__ pred_class,
    const float* __restrict__ pred_v,
    const float* __restrict__ targets,
    float* __restrict__ partial,
    unsigned int* __restrict__ ctr,
    float* __restrict__ out)
{
    __shared__ float s_predv[4][N_DIM];
    __shared__ float s_fin[4][4];
    __shared__ float s_red[4];
    __shared__ unsigned int s_ticket;

    const int tid = threadIdx.x;
    const int l   = tid & 63;
    const int w   = tid >> 6;
    const unsigned long long lt = (1ull << l) - 1ull;
    const int wave_id = blockIdx.x * 4 + w;   // 8192 waves, 2 rows each

    float acc_pick = 0.f, acc_dsq = 0.f, acc_multi = 0.f;
    int   acc_tc = 0;

#pragma unroll
    for (int i = 0; i < 2; ++i) {
        const int b = i * (NBLK * 4) + wave_id;
        const float* lgp = pred_class + (size_t)b * (2 * F_DIM);
        const float* pvp = pred_v     + (size_t)b * N_DIM;
        const float* tgp = targets    + (size_t)b * T_DIM;

        // ---- issue all row loads up front (independent, coalesced) ----
        float4 g0 = *(const float4*)(lgp + 8 * l);          // f = 4l, 4l+1
        float4 g1 = *(const float4*)(lgp + 8 * l + 4);      // f = 4l+2, 4l+3
        float4 g2 = *(const float4*)(lgp + 512 + 8 * l);    // f = 256+4l, 257+4l
        float4 g3 = *(const float4*)(lgp + 512 + 8 * l + 4);// f = 258+4l, 259+4l
        float4 pv = *(const float4*)(pvp + 4 * l);          // n = 4l..4l+3
        float4 tg = *(const float4*)(tgp + 4 * l);          // t = 4l..4l+3

        *(float4*)(&s_predv[w][4 * l]) = pv;                // stage for gather

        // ---- log-softmax picks: f<256 -> logp[1], f>=256 -> logp[0] ----
        float p = 0.f;
        p += pick_lp(g0.y, g0.x);
        p += pick_lp(g0.w, g0.z);
        p += pick_lp(g1.y, g1.x);
        p += pick_lp(g1.w, g1.z);
        p += pick_lp(g2.x, g2.y);
        p += pick_lp(g2.z, g2.w);
        p += pick_lp(g3.x, g3.y);
        p += pick_lp(g3.z, g3.w);   // chosen = component 0 for f >= 256
        acc_pick += p;

        // ---- mask + exclusive prefix over t=4l..4l+3 via 4 ballots ----
        bool m0 = g0.y > g0.x;
        bool m1 = g0.w > g0.z;
        bool m2 = g1.y > g1.x;
        bool m3 = g1.w > g1.z;
        unsigned long long b0 = __ballot(m0);
        unsigned long long b1 = __ballot(m1);
        unsigned long long b2 = __ballot(m2);
        unsigned long long b3 = __ballot(m3);

        int e0 = __popcll(b0 & lt) + __popcll(b1 & lt)
               + __popcll(b2 & lt) + __popcll(b3 & lt);
        int e1 = e0 + (m0 ? 1 : 0);
        int e2 = e1 + (m1 ? 1 : 0);
        int e3 = e2 + (m2 ? 1 : 0);
        acc_tc += __popcll(b0) + __popcll(b1) + __popcll(b2) + __popcll(b3);

        // ---- matched gather + squared error (tc==0 rows contribute 0) ----
        float dsq = 0.f, d;
        if (m0) { d = s_predv[w][e0] - tg.x; dsq += d * d; }
        if (m1) { d = s_predv[w][e1] - tg.y; dsq += d * d; }
        if (m2) { d = s_predv[w][e2] - tg.z; dsq += d * d; }
        if (m3) { d = s_predv[w][e3] - tg.w; dsq += d * d; }
        acc_dsq += dsq;

        // ---- product over the row ----
        float prod = wave_prod(pv.x * pv.y * pv.z * pv.w);
        float pm1 = prod - 1.f;
        acc_multi += pm1 * pm1;
    }

    float pickS = wave_sum(acc_pick);
    float dsqS  = wave_sum(acc_dsq);
    if (l == 0) {
        s_fin[w][0] = pickS;
        s_fin[w][1] = acc_multi;
        s_fin[w][2] = dsqS;
        s_fin[w][3] = (float)acc_tc;
    }
    __syncthreads();

    if (tid == 0) {
        float v0 = 0.f, v1 = 0.f, v2 = 0.f, v3 = 0.f;
#pragma unroll
        for (int k = 0; k < 4; ++k) {
            v0 += s_fin[k][0]; v1 += s_fin[k][1];
            v2 += s_fin[k][2]; v3 += s_fin[k][3];
        }
        // relaxed agent-scope stores: write-through past this XCD's L2,
        // no cache-maintenance instructions emitted
        __hip_atomic_store(&partial[0 * NBLK + blockIdx.x], v0,
                           __ATOMIC_RELAXED, __HIP_MEMORY_SCOPE_AGENT);
        __hip_atomic_store(&partial[1 * NBLK + blockIdx.x], v1,
                           __ATOMIC_RELAXED, __HIP_MEMORY_SCOPE_AGENT);
        __hip_atomic_store(&partial[2 * NBLK + blockIdx.x], v2 * (1.f / (float)T_DIM),
                           __ATOMIC_RELAXED, __HIP_MEMORY_SCOPE_AGENT);
        __hip_atomic_store(&partial[3 * NBLK + blockIdx.x], v3 * (1.f / (float)T_DIM),
                           __ATOMIC_RELAXED, __HIP_MEMORY_SCOPE_AGENT);
        // manual release: stores reach the coherence point before the ticket
        asm volatile("s_waitcnt vmcnt(0)" ::: "memory");
        s_ticket = __hip_atomic_fetch_add(ctr, 1u,
                           __ATOMIC_RELAXED, __HIP_MEMORY_SCOPE_AGENT);
    }
    __syncthreads();

    if (s_ticket != NBLK - 1) return;            // block-uniform exit

    // ---- last block: deterministic fixed-order final reduction ----
    float v = 0.f;
#pragma unroll
    for (int i = 0; i < NBLK / 64; ++i)
        v += __hip_atomic_load(&partial[w * NBLK + i * 64 + l],
                               __ATOMIC_RELAXED, __HIP_MEMORY_SCOPE_AGENT);
    v = wave_sum(v);
    if (l == 0) s_red[w] = v;
    __syncthreads();

    if (tid == 0) {
        float loss_label = -s_red[0] / ((float)B_TOT * (float)F_DIM);
        float loss_multi = s_red[1] / (float)B_TOT;
        float loss_true  = s_red[2] / (float)B_TOT;
        float f1         = s_red[3] / (float)B_TOT;
        float r = loss_multi + loss_true;
        out[0] = loss_label + r;
        out[1] = loss_label;
        out[2] = r;
        out[3] = loss_multi;
        out[4] = loss_true;
        out[5] = f1;
    }
}

extern "C" void kernel_launch(void* const* d_in, const int* in_sizes, int n_in,
                              void* d_out, int out_size, void* d_ws, size_t ws_size,
                              hipStream_t stream) {
    const float* pred_class = (const float*)d_in[0];
    const float* pred_v     = (const float*)d_in[1];
    const float* targets    = (const float*)d_in[2];

    float* partial = (float*)d_ws;                        // 4*NBLK floats = 32 KB
    unsigned int* ctr = (unsigned int*)((char*)d_ws + 4 * NBLK * sizeof(float));

    hipMemsetAsync(ctr, 0, sizeof(unsigned int), stream); // reset ticket each call
    setcrit_fused<<<NBLK, 256, 0, stream>>>(pred_class, pred_v, targets,
                                            partial, ctr, (float*)d_out);
}

// Round 8
// 25.105 us; speedup vs baseline: 3.5548x; 1.7325x over previous
//
#include <hip/hip_runtime.h>

#define B_TOT 16384
#define F_DIM 512
#define T_DIM 256
#define N_DIM 256
#define NBLK  2048

// keep a float4 load result live (scalar operands: f4 aggregates are not
// directly expressible in "v" constraints on gfx950)
#define PIN4(v) asm volatile("" :: "v"((v).x), "v"((v).y), "v"((v).z), "v"((v).w))

__device__ __forceinline__ float wave_sum(float v) {
#pragma unroll
    for (int o = 32; o; o >>= 1) v += __shfl_xor(v, o, 64);
    return v;
}
__device__ __forceinline__ float wave_prod(float v) {
#pragma unroll
    for (int o = 32; o; o >>= 1) v *= __shfl_xor(v, o, 64);
    return v;
}
// logp of the chosen logit: chosen - lse(chosen,other) == -log(1+exp(other-chosen))
__device__ __forceinline__ float pick_lp(float chosen, float other) {
    return -__logf(1.f + __expf(other - chosen));
}

// One wave per row, 2 rows per wave, BOTH rows' loads issued up front.
// The PIN4s pin all 12 float4 payloads live simultaneously: round 4-6
// counters showed the scheduler otherwise sinks loads and recycles 32 VGPRs,
// serializing the stream (latency-bound at 2.3 TB/s). Pin -> 12-deep MLP.
__global__ __launch_bounds__(256) void setcrit_stage1(
    const float* __restrict__ pred_class,
    const float* __restrict__ pred_v,
    const float* __restrict__ targets,
    float* __restrict__ partial)
{
    __shared__ float s_predv[2][4][N_DIM];
    __shared__ float s_fin[4][4];

    const int tid = threadIdx.x;
    const int l   = tid & 63;
    const int w   = tid >> 6;
    const unsigned long long lt = (1ull << l) - 1ull;
    const int wave_id = blockIdx.x * 4 + w;     // 8192 waves
    const int rA = wave_id;                     // row 0
    const int rB = wave_id + NBLK * 4;          // row 1

    const float* lgA = pred_class + (size_t)rA * (2 * F_DIM);
    const float* lgB = pred_class + (size_t)rB * (2 * F_DIM);

    // ---- issue all 12 loads back-to-back (coalesced, independent) ----
    float4 a0 = *(const float4*)(lgA + 8 * l);
    float4 a1 = *(const float4*)(lgA + 8 * l + 4);
    float4 a2 = *(const float4*)(lgA + 512 + 8 * l);
    float4 a3 = *(const float4*)(lgA + 512 + 8 * l + 4);
    float4 pvA = *(const float4*)(pred_v  + (size_t)rA * N_DIM + 4 * l);
    float4 tgA = *(const float4*)(targets + (size_t)rA * T_DIM + 4 * l);
    float4 b0 = *(const float4*)(lgB + 8 * l);
    float4 b1 = *(const float4*)(lgB + 8 * l + 4);
    float4 b2 = *(const float4*)(lgB + 512 + 8 * l);
    float4 b3 = *(const float4*)(lgB + 512 + 8 * l + 4);
    float4 pvB = *(const float4*)(pred_v  + (size_t)rB * N_DIM + 4 * l);
    float4 tgB = *(const float4*)(targets + (size_t)rB * T_DIM + 4 * l);

    // pin: all 12 payloads must be in registers here (one clustered wait)
    PIN4(a0); PIN4(a1); PIN4(a2); PIN4(a3); PIN4(pvA); PIN4(tgA);
    PIN4(b0); PIN4(b1); PIN4(b2); PIN4(b3); PIN4(pvB); PIN4(tgB);

    // stage pred_v rows for the gather (wave-private slices; within-wave
    // ds_write -> ds_read ordering needs no barrier)
    *(float4*)(&s_predv[0][w][4 * l]) = pvA;
    *(float4*)(&s_predv[1][w][4 * l]) = pvB;

    float acc_pick = 0.f, acc_dsq = 0.f, acc_multi = 0.f;
    int   acc_tc = 0;

    // ======== row A ========
    {
        float p = 0.f;
        p += pick_lp(a0.y, a0.x);
        p += pick_lp(a0.w, a0.z);
        p += pick_lp(a1.y, a1.x);
        p += pick_lp(a1.w, a1.z);
        p += pick_lp(a2.x, a2.y);
        p += pick_lp(a2.z, a2.w);
        p += pick_lp(a3.x, a3.y);
        p += pick_lp(a3.z, a3.w);
        acc_pick += p;

        bool m0 = a0.y > a0.x;
        bool m1 = a0.w > a0.z;
        bool m2 = a1.y > a1.x;
        bool m3 = a1.w > a1.z;
        unsigned long long q0 = __ballot(m0);
        unsigned long long q1 = __ballot(m1);
        unsigned long long q2 = __ballot(m2);
        unsigned long long q3 = __ballot(m3);

        int e0 = __popcll(q0 & lt) + __popcll(q1 & lt)
               + __popcll(q2 & lt) + __popcll(q3 & lt);
        int e1 = e0 + (m0 ? 1 : 0);
        int e2 = e1 + (m1 ? 1 : 0);
        int e3 = e2 + (m2 ? 1 : 0);
        acc_tc += __popcll(q0) + __popcll(q1) + __popcll(q2) + __popcll(q3);

        float dsq = 0.f, d;
        if (m0) { d = s_predv[0][w][e0] - tgA.x; dsq += d * d; }
        if (m1) { d = s_predv[0][w][e1] - tgA.y; dsq += d * d; }
        if (m2) { d = s_predv[0][w][e2] - tgA.z; dsq += d * d; }
        if (m3) { d = s_predv[0][w][e3] - tgA.w; dsq += d * d; }
        acc_dsq += dsq;

        float prod = wave_prod(pvA.x * pvA.y * pvA.z * pvA.w);
        float pm1 = prod - 1.f;
        acc_multi += pm1 * pm1;
    }

    // ======== row B ========
    {
        float p = 0.f;
        p += pick_lp(b0.y, b0.x);
        p += pick_lp(b0.w, b0.z);
        p += pick_lp(b1.y, b1.x);
        p += pick_lp(b1.w, b1.z);
        p += pick_lp(b2.x, b2.y);
        p += pick_lp(b2.z, b2.w);
        p += pick_lp(b3.x, b3.y);
        p += pick_lp(b3.z, b3.w);
        acc_pick += p;

        bool m0 = b0.y > b0.x;
        bool m1 = b0.w > b0.z;
        bool m2 = b1.y > b1.x;
        bool m3 = b1.w > b1.z;
        unsigned long long q0 = __ballot(m0);
        unsigned long long q1 = __ballot(m1);
        unsigned long long q2 = __ballot(m2);
        unsigned long long q3 = __ballot(m3);

        int e0 = __popcll(q0 & lt) + __popcll(q1 & lt)
               + __popcll(q2 & lt) + __popcll(q3 & lt);
        int e1 = e0 + (m0 ? 1 : 0);
        int e2 = e1 + (m1 ? 1 : 0);
        int e3 = e2 + (m2 ? 1 : 0);
        acc_tc += __popcll(q0) + __popcll(q1) + __popcll(q2) + __popcll(q3);

        float dsq = 0.f, d;
        if (m0) { d = s_predv[1][w][e0] - tgB.x; dsq += d * d; }
        if (m1) { d = s_predv[1][w][e1] - tgB.y; dsq += d * d; }
        if (m2) { d = s_predv[1][w][e2] - tgB.z; dsq += d * d; }
        if (m3) { d = s_predv[1][w][e3] - tgB.w; dsq += d * d; }
        acc_dsq += dsq;

        float prod = wave_prod(pvB.x * pvB.y * pvB.z * pvB.w);
        float pm1 = prod - 1.f;
        acc_multi += pm1 * pm1;
    }

    float pickS = wave_sum(acc_pick);
    float dsqS  = wave_sum(acc_dsq);
    if (l == 0) {
        s_fin[w][0] = pickS;
        s_fin[w][1] = acc_multi;
        s_fin[w][2] = dsqS;
        s_fin[w][3] = (float)acc_tc;
    }
    __syncthreads();
    if (tid == 0) {
        float v0 = 0.f, v1 = 0.f, v2 = 0.f, v3 = 0.f;
#pragma unroll
        for (int k = 0; k < 4; ++k) {
            v0 += s_fin[k][0]; v1 += s_fin[k][1];
            v2 += s_fin[k][2]; v3 += s_fin[k][3];
        }
        partial[0 * NBLK + blockIdx.x] = v0;
        partial[1 * NBLK + blockIdx.x] = v1;
        partial[2 * NBLK + blockIdx.x] = v2 * (1.f / (float)T_DIM);
        partial[3 * NBLK + blockIdx.x] = v3 * (1.f / (float)T_DIM);
    }
}

// Wave w reduces component w via 8 independent float4 loads/lane, one
// shuffle tree, one barrier.
__global__ __launch_bounds__(256) void setcrit_stage2(
    const float* __restrict__ partial, float* __restrict__ out)
{
    __shared__ float s_red[4];
    const int tid = threadIdx.x;
    const int l   = tid & 63;
    const int w   = tid >> 6;

    const float4* p4 = (const float4*)(partial + w * NBLK);
    float4 v4 = make_float4(0.f, 0.f, 0.f, 0.f);
#pragma unroll
    for (int i = 0; i < NBLK / 256; ++i) {
        float4 t = p4[i * 64 + l];
        v4.x += t.x; v4.y += t.y; v4.z += t.z; v4.w += t.w;
    }
    float v = wave_sum((v4.x + v4.y) + (v4.z + v4.w));
    if (l == 0) s_red[w] = v;
    __syncthreads();

    if (tid == 0) {
        float loss_label = -s_red[0] / ((float)B_TOT * (float)F_DIM);
        float loss_multi = s_red[1] / (float)B_TOT;
        float loss_true  = s_red[2] / (float)B_TOT;
        float f1         = s_red[3] / (float)B_TOT;
        float r = loss_multi + loss_true;
        out[0] = loss_label + r;
        out[1] = loss_label;
        out[2] = r;
        out[3] = loss_multi;
        out[4] = loss_true;
        out[5] = f1;
    }
}

extern "C" void kernel_launch(void* const* d_in, const int* in_sizes, int n_in,
                              void* d_out, int out_size, void* d_ws, size_t ws_size,
                              hipStream_t stream) {
    const float* pred_class = (const float*)d_in[0];
    const float* pred_v     = (const float*)d_in[1];
    const float* targets    = (const float*)d_in[2];
    float* partial = (float*)d_ws;  // 4 * NBLK floats = 32 KB

    setcrit_stage1<<<NBLK, 256, 0, stream>>>(pred_class, pred_v, targets, partial);
    setcrit_stage2<<<1, 256, 0, stream>>>(partial, (float*)d_out);
}